// Round 2
// baseline (648.371 us; speedup 1.0000x reference)
//
#include <hip/hip_runtime.h>
#include <hip/hip_bf16.h>

// ShiftWindAttention on MI355X (gfx950), bf16 MFMA pipeline.
// ws layout (bf16 elems): wqt 1,572,864 | wot 524,288 | xb 33,554,432/S | qkv 201,326,592/S
// Attention output is written into the q-columns of qkv (cols 0..1023 of stride 3072),
// so no separate att buffer is needed. S = batch-chunk factor chosen from ws_size.

typedef __attribute__((ext_vector_type(4))) float f32x4;
typedef __attribute__((ext_vector_type(8))) __bf16 bf16x8;
typedef __attribute__((ext_vector_type(8))) unsigned short u16x8;

__device__ __forceinline__ unsigned short f2bf(float f) {
  __hip_bfloat16 h = __float2bfloat16(f);
  return __builtin_bit_cast(unsigned short, h);
}
__device__ __forceinline__ float bf2f(unsigned short u) {
  return __builtin_bit_cast(float, ((unsigned int)u) << 16);
}

#define GLL16(gsrc, ldst)                                                              \
  __builtin_amdgcn_global_load_lds((const __attribute__((address_space(1))) void*)(gsrc), \
                                   (__attribute__((address_space(3))) void*)(ldst), 16, 0, 0)

// ---------------- conversion kernels ----------------
__global__ __launch_bounds__(256) void cvt_x_kernel(const float* __restrict__ in,
                                                    unsigned short* __restrict__ out, int n4) {
  int i = blockIdx.x * blockDim.x + threadIdx.x;
  int stride = gridDim.x * blockDim.x;
  for (; i < n4; i += stride) {
    float4 v = reinterpret_cast<const float4*>(in)[i];
    ushort4 o;
    o.x = f2bf(v.x); o.y = f2bf(v.y); o.z = f2bf(v.z); o.w = f2bf(v.w);
    reinterpret_cast<ushort4*>(out)[i] = o;
  }
}

// in: R x C fp32 row-major -> out: C x R bf16 (transposed)
__global__ __launch_bounds__(256) void cvt_T_kernel(const float* __restrict__ in,
                                                    unsigned short* __restrict__ out,
                                                    int R, int C) {
  int idx = blockIdx.x * 256 + threadIdx.x;
  if (idx < R * C) {
    int r = idx / C, c = idx - r * C;
    out[(size_t)c * R + r] = f2bf(in[idx]);
  }
}

// ---------------- GEMM: C[M,N] = A[M,K] * B[N,K]^T  (both bf16, B pre-transposed) ----------------
// m97 structure: 128x128 tile, BK=32, 4 waves (2x2 of 64x64), global_load_lds w=16.
template <bool OUT_BF16>
__global__ __launch_bounds__(256) void gemm_bt(const unsigned short* __restrict__ A, int lda,
                                               const unsigned short* __restrict__ B, int ldb,
                                               void* __restrict__ Cv, int ldc,
                                               const float* __restrict__ bias,
                                               int N, int K) {
  __shared__ alignas(16) unsigned short As[128 * 32];
  __shared__ alignas(16) unsigned short Bs[128 * 32];
  const int tid = threadIdx.x;
  const int lane = tid & 63;
  const int wave = tid >> 6;
  const int nbn = N >> 7;
  const int nwg = gridDim.x;
  const int b0 = blockIdx.x;
  // bijective XCD swizzle (nwg % 8 == 0 for all our grids)
  const int swz = (b0 & 7) * (nwg >> 3) + (b0 >> 3);
  const int bm = swz / nbn, bn = swz - bm * nbn;
  const int m0 = bm << 7, n0 = bn << 7;
  const int wm = (wave >> 1) << 6;
  const int wn = (wave & 1) << 6;
  const int r0 = lane & 15, kh = lane >> 4;

  // staging: 8192 B per tile = 4 waves x 2 chunks x (64 lanes x 16 B)
  const int e0 = (wave * 2 + 0) * 512 + lane * 8;  // element offset in tile
  const int e1 = (wave * 2 + 1) * 512 + lane * 8;
  const int ra0 = e0 >> 5, ca0 = e0 & 31;
  const int ra1 = e1 >> 5, ca1 = e1 & 31;

  f32x4 acc[4][4] = {};
  const int nkt = K >> 5;
  for (int kt = 0; kt < nkt; ++kt) {
    const int k0 = kt << 5;
    if (kt) __syncthreads();
    GLL16(A + (size_t)(m0 + ra0) * lda + k0 + ca0, &As[(wave * 2 + 0) * 512]);
    GLL16(A + (size_t)(m0 + ra1) * lda + k0 + ca1, &As[(wave * 2 + 1) * 512]);
    GLL16(B + (size_t)(n0 + ra0) * ldb + k0 + ca0, &Bs[(wave * 2 + 0) * 512]);
    GLL16(B + (size_t)(n0 + ra1) * ldb + k0 + ca1, &Bs[(wave * 2 + 1) * 512]);
    __syncthreads();
    bf16x8 af[4], bfr[4];
#pragma unroll
    for (int mi = 0; mi < 4; ++mi)
      af[mi] = *reinterpret_cast<const bf16x8*>(&As[(wm + mi * 16 + r0) * 32 + kh * 8]);
#pragma unroll
    for (int ni = 0; ni < 4; ++ni)
      bfr[ni] = *reinterpret_cast<const bf16x8*>(&Bs[(wn + ni * 16 + r0) * 32 + kh * 8]);
#pragma unroll
    for (int mi = 0; mi < 4; ++mi)
#pragma unroll
      for (int ni = 0; ni < 4; ++ni)
        acc[mi][ni] =
            __builtin_amdgcn_mfma_f32_16x16x32_bf16(af[mi], bfr[ni], acc[mi][ni], 0, 0, 0);
  }
  // epilogue: C/D layout col = lane&15, row = (lane>>4)*4 + reg
  const int rr = kh << 2;
#pragma unroll
  for (int mi = 0; mi < 4; ++mi)
#pragma unroll
    for (int ni = 0; ni < 4; ++ni) {
      const int col = n0 + wn + ni * 16 + r0;
#pragma unroll
      for (int r = 0; r < 4; ++r) {
        const size_t row = (size_t)(m0 + wm + mi * 16 + rr + r);
        if (OUT_BF16)
          ((unsigned short*)Cv)[row * ldc + col] = f2bf(acc[mi][ni][r]);
        else
          ((float*)Cv)[row * ldc + col] = acc[mi][ni][r] + bias[col];
      }
    }
}

// ---------------- windowed attention ----------------
__device__ __forceinline__ int region_of(int wy, int wx, int t) {
  // region id in ROLLED coordinates (Swin shift mask)
  int yr = wy * 8 + (t >> 3);
  int xr = wx * 8 + (t & 7);
  int ry = (yr < 24) ? 0 : ((yr < 28) ? 1 : 2);
  int rx = (xr < 24) ? 0 : ((xr < 28) ? 1 : 2);
  return ry * 3 + rx;
}

// out: attention result written at out[token*3072 + head*64 + d] (q-columns of qkv)
__global__ __launch_bounds__(256) void win_attn(const unsigned short* __restrict__ qkv,
                                                const float* __restrict__ bias_table,
                                                unsigned short* __restrict__ out,
                                                int nb16) {
  __shared__ alignas(16) unsigned short vt[4][64][72];  // V^T per wave: vt[d][j]
  __shared__ alignas(16) unsigned short pl[4][64][72];  // P per wave:  pl[i][j]
  __shared__ unsigned short bias_sh[225 * 16];

  const int tid = threadIdx.x, lane = tid & 63, wave = tid >> 6;
  const int bid = blockIdx.x;
  const int g = bid / nb16;  // shift group: 0 -> shift 0, 1 -> shift 4
  const int bw = bid - g * nb16;
  const int b = bw >> 4, w = bw & 15;
  const int wy = w >> 2, wx = w & 3;
  const int shift = g ? 4 : 0;

  for (int i = tid; i < 225 * 16; i += 256) bias_sh[i] = f2bf(bias_table[i]);
  __syncthreads();

  const int r0 = lane & 15, hi4 = lane >> 4;

  for (int hh = 0; hh < 2; ++hh) {
    const int head = g * 8 + wave * 2 + hh;
    const int qcol = head * 64;

    // load Q,K fragments directly from global (A-style: row = lane&15, k = (lane>>4)*8+j)
    bf16x8 qf[4][2], kf[4][2];
#pragma unroll
    for (int mi = 0; mi < 4; ++mi) {
      const int t = mi * 16 + r0;
      const int y = (wy * 8 + (t >> 3) + shift) & 31;
      const int x = (wx * 8 + (t & 7) + shift) & 31;
      const size_t base = (size_t)((b << 10) + (y << 5) + x) * 3072 + qcol;
#pragma unroll
      for (int kb = 0; kb < 2; ++kb) {
        const int d = kb * 32 + hi4 * 8;
        qf[mi][kb] = *reinterpret_cast<const bf16x8*>(&qkv[base + d]);
        kf[mi][kb] = *reinterpret_cast<const bf16x8*>(&qkv[base + 1024 + d]);
      }
    }

    // stage V transposed into LDS: vt[d][j] = V[j][d]
    {
      const int y = (wy * 8 + (lane >> 3) + shift) & 31;
      const int x = (wx * 8 + (lane & 7) + shift) & 31;
      const unsigned short* vsrc =
          qkv + (size_t)((b << 10) + (y << 5) + x) * 3072 + 2048 + qcol;
#pragma unroll
      for (int d0 = 0; d0 < 8; ++d0) {
        u16x8 vv = *reinterpret_cast<const u16x8*>(&vsrc[d0 * 8]);
#pragma unroll
        for (int jj = 0; jj < 8; ++jj) vt[wave][d0 * 8 + jj][lane] = vv[jj];
      }
    }

    // S = Q K^T (fp32 accum)
    f32x4 s[4][4] = {};
#pragma unroll
    for (int mi = 0; mi < 4; ++mi)
#pragma unroll
      for (int ni = 0; ni < 4; ++ni) {
        s[mi][ni] = __builtin_amdgcn_mfma_f32_16x16x32_bf16(qf[mi][0], kf[ni][0], s[mi][ni], 0, 0, 0);
        s[mi][ni] = __builtin_amdgcn_mfma_f32_16x16x32_bf16(qf[mi][1], kf[ni][1], s[mi][ni], 0, 0, 0);
      }

    // scale + bias (+ shift mask), wave-parallel softmax over rows (16-lane groups)
    int rj[4];
#pragma unroll
    for (int ni = 0; ni < 4; ++ni) rj[ni] = region_of(wy, wx, ni * 16 + r0);
    float rinv[4][4];
#pragma unroll
    for (int mi = 0; mi < 4; ++mi) {
#pragma unroll
      for (int r = 0; r < 4; ++r) {
        const int it = mi * 16 + hi4 * 4 + r;
        const int iy = it >> 3, ix = it & 7;
        const int ri = region_of(wy, wx, it);
        float vals[4], vmax = -1e30f;
#pragma unroll
        for (int ni = 0; ni < 4; ++ni) {
          const int jt = ni * 16 + r0;
          const int ridx = (iy - (jt >> 3) + 7) * 15 + (ix - (jt & 7) + 7);
          float v = s[mi][ni][r] * 0.125f + bf2f(bias_sh[ridx * 16 + head]);
          if (g && ri != rj[ni]) v = -1e9f;
          vals[ni] = v;
          vmax = fmaxf(vmax, v);
        }
        vmax = fmaxf(vmax, __shfl_xor(vmax, 1));
        vmax = fmaxf(vmax, __shfl_xor(vmax, 2));
        vmax = fmaxf(vmax, __shfl_xor(vmax, 4));
        vmax = fmaxf(vmax, __shfl_xor(vmax, 8));
        float ssum = 0.f;
#pragma unroll
        for (int ni = 0; ni < 4; ++ni) {
          float p = __expf(vals[ni] - vmax);
          ssum += p;
          s[mi][ni][r] = p;
        }
        ssum += __shfl_xor(ssum, 1);
        ssum += __shfl_xor(ssum, 2);
        ssum += __shfl_xor(ssum, 4);
        ssum += __shfl_xor(ssum, 8);
        rinv[mi][r] = 1.0f / ssum;
      }
    }

    // P (unnormalized, in [0,1]) -> LDS bf16
#pragma unroll
    for (int mi = 0; mi < 4; ++mi)
#pragma unroll
      for (int ni = 0; ni < 4; ++ni)
#pragma unroll
        for (int r = 0; r < 4; ++r)
          pl[wave][mi * 16 + hi4 * 4 + r][ni * 16 + r0] = f2bf(s[mi][ni][r]);

    // O = P V
    f32x4 o[4][4] = {};
#pragma unroll
    for (int kb = 0; kb < 2; ++kb) {
      bf16x8 pf[4], vf[4];
#pragma unroll
      for (int mi = 0; mi < 4; ++mi)
        pf[mi] = *reinterpret_cast<const bf16x8*>(&pl[wave][mi * 16 + r0][kb * 32 + hi4 * 8]);
#pragma unroll
      for (int di = 0; di < 4; ++di)
        vf[di] = *reinterpret_cast<const bf16x8*>(&vt[wave][di * 16 + r0][kb * 32 + hi4 * 8]);
#pragma unroll
      for (int mi = 0; mi < 4; ++mi)
#pragma unroll
        for (int di = 0; di < 4; ++di)
          o[mi][di] = __builtin_amdgcn_mfma_f32_16x16x32_bf16(pf[mi], vf[di], o[mi][di], 0, 0, 0);
    }

    // normalize rows by 1/sum and scatter back to original (unrolled) coords
#pragma unroll
    for (int mi = 0; mi < 4; ++mi)
#pragma unroll
      for (int r = 0; r < 4; ++r) {
        const int it = mi * 16 + hi4 * 4 + r;
        const int y = (wy * 8 + (it >> 3) + shift) & 31;
        const int x = (wx * 8 + (it & 7) + shift) & 31;
        unsigned short* op = out + (size_t)((b << 10) + (y << 5) + x) * 3072 + head * 64;
        const float rv = rinv[mi][r];
#pragma unroll
        for (int di = 0; di < 4; ++di) op[di * 16 + r0] = f2bf(o[mi][di][r] * rv);
      }
  }
}

// ---------------- launcher ----------------
extern "C" void kernel_launch(void* const* d_in, const int* in_sizes, int n_in,
                              void* d_out, int out_size, void* d_ws, size_t ws_size,
                              hipStream_t stream) {
  const float* x = (const float*)d_in[0];          // 65536 x 512
  const float* w_qkv = (const float*)d_in[1];      // 512 x 3072
  const float* bias_table = (const float*)d_in[2]; // 225 x 16
  const float* w_out = (const float*)d_in[3];      // 1024 x 512
  const float* b_out = (const float*)d_in[4];      // 512
  float* out = (float*)d_out;                      // 65536 x 512

  // choose batch-chunk factor S so workspace fits
  int S = 1;
  for (; S < 16; S <<= 1) {
    size_t need = 2ull * (2097152ull + 234881024ull / (size_t)S);
    if (need <= ws_size) break;
  }
  const int Mc = 65536 / S;     // tokens per chunk
  const int nb = 64 / S;        // batches per chunk

  unsigned short* wqt = (unsigned short*)d_ws;               // 1,572,864 elems
  unsigned short* wot = wqt + (size_t)1572864;               //   524,288
  unsigned short* xb  = wot + (size_t)524288;                // Mc*512
  unsigned short* qkv = xb + (size_t)Mc * 512;               // Mc*3072

  cvt_T_kernel<<<6144, 256, 0, stream>>>(w_qkv, wqt, 512, 3072);
  cvt_T_kernel<<<2048, 256, 0, stream>>>(w_out, wot, 1024, 512);

  for (int c = 0; c < S; ++c) {
    const float* xc = x + (size_t)c * Mc * 512;
    cvt_x_kernel<<<2048, 256, 0, stream>>>(xc, xb, Mc * 128);
    gemm_bt<true><<<(Mc >> 7) * 24, 256, 0, stream>>>(xb, 512, wqt, 512, (void*)qkv, 3072,
                                                      nullptr, 3072, 512);
    win_attn<<<2 * nb * 16, 256, 0, stream>>>(qkv, bias_table, qkv, nb * 16);
    gemm_bt<false><<<(Mc >> 7) * 4, 256, 0, stream>>>(qkv, 3072, wot, 1024,
                                                      (void*)(out + (size_t)c * Mc * 512), 512,
                                                      b_out, 512, 1024);
  }
}

// Round 3
// 592.421 us; speedup vs baseline: 1.0944x; 1.0944x over previous
//
#include <hip/hip_runtime.h>
#include <hip/hip_bf16.h>

// ShiftWindAttention on MI355X (gfx950), bf16 MFMA pipeline.
// Round 3: 256x256 8-phase GEMM (T2 swizzle + T3/T4 counted vmcnt + T5 setprio).

typedef __attribute__((ext_vector_type(4))) float f32x4;
typedef __attribute__((ext_vector_type(8))) __bf16 bf16x8;
typedef __attribute__((ext_vector_type(8))) unsigned short u16x8;

__device__ __forceinline__ unsigned short f2bf(float f) {
  __hip_bfloat16 h = __float2bfloat16(f);
  return __builtin_bit_cast(unsigned short, h);
}
__device__ __forceinline__ float bf2f(unsigned short u) {
  return __builtin_bit_cast(float, ((unsigned int)u) << 16);
}

#define GLL16(gsrc, ldst)                                                              \
  __builtin_amdgcn_global_load_lds((const __attribute__((address_space(1))) void*)(gsrc), \
                                   (__attribute__((address_space(3))) void*)(ldst), 16, 0, 0)

// st_16x32 XOR swizzle (involution): toggle byte-bit5 with byte-bit9
#define SWZ(x) ((x) ^ ((((x) >> 9) & 1) << 5))

#define MFMA_BF16 __builtin_amdgcn_mfma_f32_16x16x32_bf16

// ---------------- conversion kernels ----------------
__global__ __launch_bounds__(256) void cvt_x_kernel(const float* __restrict__ in,
                                                    unsigned short* __restrict__ out, int n4) {
  int i = blockIdx.x * blockDim.x + threadIdx.x;
  int stride = gridDim.x * blockDim.x;
  for (; i < n4; i += stride) {
    float4 v = reinterpret_cast<const float4*>(in)[i];
    ushort4 o;
    o.x = f2bf(v.x); o.y = f2bf(v.y); o.z = f2bf(v.z); o.w = f2bf(v.w);
    reinterpret_cast<ushort4*>(out)[i] = o;
  }
}

__global__ __launch_bounds__(256) void cvt_T_kernel(const float* __restrict__ in,
                                                    unsigned short* __restrict__ out,
                                                    int R, int C) {
  int idx = blockIdx.x * 256 + threadIdx.x;
  if (idx < R * C) {
    int r = idx / C, c = idx - r * C;
    out[(size_t)c * R + r] = f2bf(in[idx]);
  }
}

// ---------------- 256x256 8-phase GEMM: C[M,N] = A[M,K] * B[N,K]^T ----------------
// 512 threads = 8 waves (2M x 4N), per-wave 128x64 out, BK=64, 2-deep LDS dbuf 128KiB.
// Stage order per tile u: ph1 A0(u+1) ph2 A1(u+1) ph3 B0(u+2) ph4 B1(u+2); vmcnt(4) @ph4.
template <bool OUT_BF16>
__global__ __launch_bounds__(512, 2) void gemm8p(const unsigned short* __restrict__ A, int lda,
                                                 const unsigned short* __restrict__ B, int ldb,
                                                 void* __restrict__ Cv, int ldc,
                                                 const float* __restrict__ bias, int N, int K) {
  __shared__ alignas(16) unsigned char lds[131072];  // A: [0,64K) B: [64K,128K)
  const int tid = threadIdx.x, lane = tid & 63, wave = tid >> 6;
  const int wm = wave >> 2, wn = wave & 3;
  const int nbn = N >> 8;
  const int nwg = gridDim.x;
  const int b0 = blockIdx.x;
  const int sb = (b0 & 7) * (nwg >> 3) + (b0 >> 3);  // bijective: nwg % 8 == 0
  const int bm = sb / nbn, bn = sb - bm * nbn;
  const int m0 = bm << 8, n0 = bn << 8;
  const int nkt = K >> 6;

  // staging geometry: thread covers linear LDS bytes d0=[wave*1024+lane*16] and d0+8192
  // within a 16KiB half-tile; global source is inverse-swizzled (rule #21).
  const int d0 = wave * 1024 + lane * 16;
  const int r0g = d0 >> 7;                  // 0..63
  const int c0 = (SWZ(d0) & 127) >> 1;      // elem col (16B-aligned)
  const int d1 = d0 + 8192;
  const int r1g = d1 >> 7;                  // 64..127
  const int c1 = (SWZ(d1) & 127) >> 1;

  const int fr = lane & 15, fk = lane >> 4;
  const int fkb = fk * 16;                  // byte offset of k-group within 128B row

  auto STAGE = [&](const unsigned short* __restrict__ S, int ld, int rbase, int h, int kt,
                   int bufo, int breg) {
    const unsigned short* s0 = S + (size_t)(rbase + h * 128 + r0g) * ld + kt * 64 + c0;
    const unsigned short* s1 = S + (size_t)(rbase + h * 128 + r1g) * ld + kt * 64 + c1;
    auto* lb = &lds[breg + bufo + h * 16384 + wave * 1024];  // wave-uniform dest
    GLL16(s0, lb);
    GLL16(s1, lb + 8192);
  };
  auto LDA_ = [&](int bufo, int mi, int kb) -> bf16x8 {
    const int e = (mi * 16 + fr) * 128 + kb * 64 + fkb;
    return *reinterpret_cast<const bf16x8*>(&lds[bufo + wm * 16384 + SWZ(e)]);
  };
  auto LDB_ = [&](int bufo, int ni, int kb) -> bf16x8 {
    const int e = ((wn & 1) * 64 + ni * 16 + fr) * 128 + kb * 64 + fkb;
    return *reinterpret_cast<const bf16x8*>(&lds[65536 + bufo + (wn >> 1) * 16384 + SWZ(e)]);
  };

  // prologue: tile0 (A0,A1,B0,B1) + tile1 (B0,B1) -> 12 loads; vmcnt(4) => tile0 landed
  STAGE(A, lda, m0, 0, 0, 0, 0);
  STAGE(A, lda, m0, 1, 0, 0, 0);
  STAGE(B, ldb, n0, 0, 0, 0, 65536);
  STAGE(B, ldb, n0, 1, 0, 0, 65536);
  {
    const int k1 = (nkt > 1) ? 1 : 0;
    STAGE(B, ldb, n0, 0, k1, 32768, 65536);
    STAGE(B, ldb, n0, 1, k1, 32768, 65536);
  }
  asm volatile("s_waitcnt vmcnt(4)" ::: "memory");
  __builtin_amdgcn_s_barrier();

  f32x4 acc[8][4] = {};
  bf16x8 Af[4][2], Bf[4][2];

  for (int u = 0; u < nkt; ++u) {
    const int bufo = (u & 1) * 32768;
    const int bnx = ((u + 1) & 1) * 32768;
    const int kA = (u + 1 < nkt) ? u + 1 : nkt - 1;
    const int kB = (u + 2 < nkt) ? u + 2 : nkt - 1;

    // ---- phase 1: read A m0-3 (8) + B n0-1 (4); stage A0(u+1); MFMA quad (m0-3 x n0-1)
#pragma unroll
    for (int mi = 0; mi < 4; ++mi) { Af[mi][0] = LDA_(bufo, mi, 0); Af[mi][1] = LDA_(bufo, mi, 1); }
#pragma unroll
    for (int ni = 0; ni < 2; ++ni) { Bf[ni][0] = LDB_(bufo, ni, 0); Bf[ni][1] = LDB_(bufo, ni, 1); }
    STAGE(A, lda, m0, 0, kA, bnx, 0);
    __builtin_amdgcn_s_barrier();
    asm volatile("s_waitcnt lgkmcnt(0)" ::: "memory");
    __builtin_amdgcn_s_setprio(1);
#pragma unroll
    for (int mi = 0; mi < 4; ++mi)
#pragma unroll
      for (int ni = 0; ni < 2; ++ni) {
        acc[mi][ni] = MFMA_BF16(Af[mi][0], Bf[ni][0], acc[mi][ni], 0, 0, 0);
        acc[mi][ni] = MFMA_BF16(Af[mi][1], Bf[ni][1], acc[mi][ni], 0, 0, 0);
      }
    __builtin_amdgcn_s_setprio(0);
    __builtin_amdgcn_s_barrier();

    // ---- phase 2: read B n2-3 (4); stage A1(u+1); MFMA (m0-3 x n2-3)
#pragma unroll
    for (int ni = 2; ni < 4; ++ni) { Bf[ni][0] = LDB_(bufo, ni, 0); Bf[ni][1] = LDB_(bufo, ni, 1); }
    STAGE(A, lda, m0, 1, kA, bnx, 0);
    __builtin_amdgcn_s_barrier();
    asm volatile("s_waitcnt lgkmcnt(0)" ::: "memory");
    __builtin_amdgcn_s_setprio(1);
#pragma unroll
    for (int mi = 0; mi < 4; ++mi)
#pragma unroll
      for (int ni = 2; ni < 4; ++ni) {
        acc[mi][ni] = MFMA_BF16(Af[mi][0], Bf[ni][0], acc[mi][ni], 0, 0, 0);
        acc[mi][ni] = MFMA_BF16(Af[mi][1], Bf[ni][1], acc[mi][ni], 0, 0, 0);
      }
    __builtin_amdgcn_s_setprio(0);
    __builtin_amdgcn_s_barrier();

    // ---- phase 3: read A m4-7 (8); stage B0(u+2); MFMA (m4-7 x n0-1) [B regs held]
#pragma unroll
    for (int mi = 0; mi < 4; ++mi) { Af[mi][0] = LDA_(bufo, 4 + mi, 0); Af[mi][1] = LDA_(bufo, 4 + mi, 1); }
    STAGE(B, ldb, n0, 0, kB, bufo, 65536);
    __builtin_amdgcn_s_barrier();
    asm volatile("s_waitcnt lgkmcnt(0)" ::: "memory");
    __builtin_amdgcn_s_setprio(1);
#pragma unroll
    for (int mi = 0; mi < 4; ++mi)
#pragma unroll
      for (int ni = 0; ni < 2; ++ni) {
        acc[4 + mi][ni] = MFMA_BF16(Af[mi][0], Bf[ni][0], acc[4 + mi][ni], 0, 0, 0);
        acc[4 + mi][ni] = MFMA_BF16(Af[mi][1], Bf[ni][1], acc[4 + mi][ni], 0, 0, 0);
      }
    __builtin_amdgcn_s_setprio(0);
    __builtin_amdgcn_s_barrier();

    // ---- phase 4: no reads; stage B1(u+2); vmcnt(4) certifies tile u+1; MFMA (m4-7 x n2-3)
    STAGE(B, ldb, n0, 1, kB, bufo, 65536);
    asm volatile("s_waitcnt vmcnt(4)" ::: "memory");
    __builtin_amdgcn_s_barrier();
    __builtin_amdgcn_s_setprio(1);
#pragma unroll
    for (int mi = 0; mi < 4; ++mi)
#pragma unroll
      for (int ni = 2; ni < 4; ++ni) {
        acc[4 + mi][ni] = MFMA_BF16(Af[mi][0], Bf[ni][0], acc[4 + mi][ni], 0, 0, 0);
        acc[4 + mi][ni] = MFMA_BF16(Af[mi][1], Bf[ni][1], acc[4 + mi][ni], 0, 0, 0);
      }
    __builtin_amdgcn_s_setprio(0);
    __builtin_amdgcn_s_barrier();
  }

  // epilogue: C/D layout col = lane&15, row = (lane>>4)*4 + r
  const int er = fk << 2;
#pragma unroll
  for (int mi = 0; mi < 8; ++mi)
#pragma unroll
    for (int ni = 0; ni < 4; ++ni) {
      const int col = n0 + wn * 64 + ni * 16 + fr;
#pragma unroll
      for (int r = 0; r < 4; ++r) {
        const size_t row = (size_t)(m0 + wm * 128 + mi * 16 + er + r);
        if (OUT_BF16)
          ((unsigned short*)Cv)[row * ldc + col] = f2bf(acc[mi][ni][r]);
        else
          ((float*)Cv)[row * ldc + col] = acc[mi][ni][r] + bias[col];
      }
    }
}

// ---------------- windowed attention ----------------
__device__ __forceinline__ int region_of(int wy, int wx, int t) {
  int yr = wy * 8 + (t >> 3);
  int xr = wx * 8 + (t & 7);
  int ry = (yr < 24) ? 0 : ((yr < 28) ? 1 : 2);
  int rx = (xr < 24) ? 0 : ((xr < 28) ? 1 : 2);
  return ry * 3 + rx;
}

__global__ __launch_bounds__(256) void win_attn(const unsigned short* __restrict__ qkv,
                                                const float* __restrict__ bias_table,
                                                unsigned short* __restrict__ out,
                                                int nb16) {
  __shared__ alignas(16) unsigned short vt[4][64][72];
  __shared__ alignas(16) unsigned short pl[4][64][72];
  __shared__ unsigned short bias_sh[225 * 16];

  const int tid = threadIdx.x, lane = tid & 63, wave = tid >> 6;
  const int bid = blockIdx.x;
  const int g = bid / nb16;
  const int bw = bid - g * nb16;
  const int b = bw >> 4, w = bw & 15;
  const int wy = w >> 2, wx = w & 3;
  const int shift = g ? 4 : 0;

  for (int i = tid; i < 225 * 16; i += 256) bias_sh[i] = f2bf(bias_table[i]);
  __syncthreads();

  const int r0 = lane & 15, hi4 = lane >> 4;

  for (int hh = 0; hh < 2; ++hh) {
    const int head = g * 8 + wave * 2 + hh;
    const int qcol = head * 64;

    bf16x8 qf[4][2], kf[4][2];
#pragma unroll
    for (int mi = 0; mi < 4; ++mi) {
      const int t = mi * 16 + r0;
      const int y = (wy * 8 + (t >> 3) + shift) & 31;
      const int x = (wx * 8 + (t & 7) + shift) & 31;
      const size_t base = (size_t)((b << 10) + (y << 5) + x) * 3072 + qcol;
#pragma unroll
      for (int kb = 0; kb < 2; ++kb) {
        const int d = kb * 32 + hi4 * 8;
        qf[mi][kb] = *reinterpret_cast<const bf16x8*>(&qkv[base + d]);
        kf[mi][kb] = *reinterpret_cast<const bf16x8*>(&qkv[base + 1024 + d]);
      }
    }

    {
      const int y = (wy * 8 + (lane >> 3) + shift) & 31;
      const int x = (wx * 8 + (lane & 7) + shift) & 31;
      const unsigned short* vsrc =
          qkv + (size_t)((b << 10) + (y << 5) + x) * 3072 + 2048 + qcol;
#pragma unroll
      for (int d0 = 0; d0 < 8; ++d0) {
        u16x8 vv = *reinterpret_cast<const u16x8*>(&vsrc[d0 * 8]);
#pragma unroll
        for (int jj = 0; jj < 8; ++jj) vt[wave][d0 * 8 + jj][lane] = vv[jj];
      }
    }

    f32x4 s[4][4] = {};
#pragma unroll
    for (int mi = 0; mi < 4; ++mi)
#pragma unroll
      for (int ni = 0; ni < 4; ++ni) {
        s[mi][ni] = MFMA_BF16(qf[mi][0], kf[ni][0], s[mi][ni], 0, 0, 0);
        s[mi][ni] = MFMA_BF16(qf[mi][1], kf[ni][1], s[mi][ni], 0, 0, 0);
      }

    int rj[4];
#pragma unroll
    for (int ni = 0; ni < 4; ++ni) rj[ni] = region_of(wy, wx, ni * 16 + r0);
    float rinv[4][4];
#pragma unroll
    for (int mi = 0; mi < 4; ++mi) {
#pragma unroll
      for (int r = 0; r < 4; ++r) {
        const int it = mi * 16 + hi4 * 4 + r;
        const int iy = it >> 3, ix = it & 7;
        const int ri = region_of(wy, wx, it);
        float vals[4], vmax = -1e30f;
#pragma unroll
        for (int ni = 0; ni < 4; ++ni) {
          const int jt = ni * 16 + r0;
          const int ridx = (iy - (jt >> 3) + 7) * 15 + (ix - (jt & 7) + 7);
          float v = s[mi][ni][r] * 0.125f + bf2f(bias_sh[ridx * 16 + head]);
          if (g && ri != rj[ni]) v = -1e9f;
          vals[ni] = v;
          vmax = fmaxf(vmax, v);
        }
        vmax = fmaxf(vmax, __shfl_xor(vmax, 1));
        vmax = fmaxf(vmax, __shfl_xor(vmax, 2));
        vmax = fmaxf(vmax, __shfl_xor(vmax, 4));
        vmax = fmaxf(vmax, __shfl_xor(vmax, 8));
        float ssum = 0.f;
#pragma unroll
        for (int ni = 0; ni < 4; ++ni) {
          float p = __expf(vals[ni] - vmax);
          ssum += p;
          s[mi][ni][r] = p;
        }
        ssum += __shfl_xor(ssum, 1);
        ssum += __shfl_xor(ssum, 2);
        ssum += __shfl_xor(ssum, 4);
        ssum += __shfl_xor(ssum, 8);
        rinv[mi][r] = 1.0f / ssum;
      }
    }

#pragma unroll
    for (int mi = 0; mi < 4; ++mi)
#pragma unroll
      for (int ni = 0; ni < 4; ++ni)
#pragma unroll
        for (int r = 0; r < 4; ++r)
          pl[wave][mi * 16 + hi4 * 4 + r][ni * 16 + r0] = f2bf(s[mi][ni][r]);

    f32x4 o[4][4] = {};
#pragma unroll
    for (int kb = 0; kb < 2; ++kb) {
      bf16x8 pf[4], vf[4];
#pragma unroll
      for (int mi = 0; mi < 4; ++mi)
        pf[mi] = *reinterpret_cast<const bf16x8*>(&pl[wave][mi * 16 + r0][kb * 32 + hi4 * 8]);
#pragma unroll
      for (int di = 0; di < 4; ++di)
        vf[di] = *reinterpret_cast<const bf16x8*>(&vt[wave][di * 16 + r0][kb * 32 + hi4 * 8]);
#pragma unroll
      for (int mi = 0; mi < 4; ++mi)
#pragma unroll
        for (int di = 0; di < 4; ++di)
          o[mi][di] = MFMA_BF16(pf[mi], vf[di], o[mi][di], 0, 0, 0);
    }

#pragma unroll
    for (int mi = 0; mi < 4; ++mi)
#pragma unroll
      for (int r = 0; r < 4; ++r) {
        const int it = mi * 16 + hi4 * 4 + r;
        const int y = (wy * 8 + (it >> 3) + shift) & 31;
        const int x = (wx * 8 + (it & 7) + shift) & 31;
        unsigned short* op = out + (size_t)((b << 10) + (y << 5) + x) * 3072 + head * 64;
        const float rv = rinv[mi][r];
#pragma unroll
        for (int di = 0; di < 4; ++di) op[di * 16 + r0] = f2bf(o[mi][di][r] * rv);
      }
  }
}

// ---------------- launcher ----------------
extern "C" void kernel_launch(void* const* d_in, const int* in_sizes, int n_in,
                              void* d_out, int out_size, void* d_ws, size_t ws_size,
                              hipStream_t stream) {
  const float* x = (const float*)d_in[0];
  const float* w_qkv = (const float*)d_in[1];
  const float* bias_table = (const float*)d_in[2];
  const float* w_out = (const float*)d_in[3];
  const float* b_out = (const float*)d_in[4];
  float* out = (float*)d_out;

  int S = 1;
  for (; S < 16; S <<= 1) {
    size_t need = 2ull * (2097152ull + 234881024ull / (size_t)S);
    if (need <= ws_size) break;
  }
  const int Mc = 65536 / S;
  const int nb = 64 / S;

  unsigned short* wqt = (unsigned short*)d_ws;
  unsigned short* wot = wqt + (size_t)1572864;
  unsigned short* xb  = wot + (size_t)524288;
  unsigned short* qkv = xb + (size_t)Mc * 512;

  cvt_T_kernel<<<6144, 256, 0, stream>>>(w_qkv, wqt, 512, 3072);
  cvt_T_kernel<<<2048, 256, 0, stream>>>(w_out, wot, 1024, 512);

  for (int c = 0; c < S; ++c) {
    const float* xc = x + (size_t)c * Mc * 512;
    cvt_x_kernel<<<2048, 256, 0, stream>>>(xc, xb, Mc * 128);
    gemm8p<true><<<(Mc >> 8) * 12, 512, 0, stream>>>(xb, 512, wqt, 512, (void*)qkv, 3072,
                                                     nullptr, 3072, 512);
    win_attn<<<2 * nb * 16, 256, 0, stream>>>(qkv, bias_table, qkv, nb * 16);
    gemm8p<false><<<(Mc >> 8) * 2, 512, 0, stream>>>(qkv, 3072, wot, 1024,
                                                     (void*)(out + (size_t)c * Mc * 512), 512,
                                                     b_out, 512, 1024);
  }
}

// Round 4
// 581.656 us; speedup vs baseline: 1.1147x; 1.0185x over previous
//
#include <hip/hip_runtime.h>
#include <hip/hip_bf16.h>

// ShiftWindAttention on MI355X (gfx950), bf16 MFMA pipeline.
// Round 4: fix T2 swizzle -> row-based XOR (byte ^= ((row&7)<<4)), per G4 recipe.

typedef __attribute__((ext_vector_type(4))) float f32x4;
typedef __attribute__((ext_vector_type(8))) __bf16 bf16x8;
typedef __attribute__((ext_vector_type(8))) unsigned short u16x8;

__device__ __forceinline__ unsigned short f2bf(float f) {
  __hip_bfloat16 h = __float2bfloat16(f);
  return __builtin_bit_cast(unsigned short, h);
}
__device__ __forceinline__ float bf2f(unsigned short u) {
  return __builtin_bit_cast(float, ((unsigned int)u) << 16);
}

#define GLL16(gsrc, ldst)                                                              \
  __builtin_amdgcn_global_load_lds((const __attribute__((address_space(1))) void*)(gsrc), \
                                   (__attribute__((address_space(3))) void*)(ldst), 16, 0, 0)

// Row-XOR swizzle (involution): 128B rows; toggle 16B-slot bits [6:4] with row bits [2:0].
// Preserves bits 0-3 (16B chunks contiguous) and the row (bits >=7).
#define SWZ(x) ((x) ^ ((((x) >> 7) & 7) << 4))

#define MFMA_BF16 __builtin_amdgcn_mfma_f32_16x16x32_bf16

// ---------------- conversion kernels ----------------
__global__ __launch_bounds__(256) void cvt_x_kernel(const float* __restrict__ in,
                                                    unsigned short* __restrict__ out, int n4) {
  int i = blockIdx.x * blockDim.x + threadIdx.x;
  int stride = gridDim.x * blockDim.x;
  for (; i < n4; i += stride) {
    float4 v = reinterpret_cast<const float4*>(in)[i];
    ushort4 o;
    o.x = f2bf(v.x); o.y = f2bf(v.y); o.z = f2bf(v.z); o.w = f2bf(v.w);
    reinterpret_cast<ushort4*>(out)[i] = o;
  }
}

__global__ __launch_bounds__(256) void cvt_T_kernel(const float* __restrict__ in,
                                                    unsigned short* __restrict__ out,
                                                    int R, int C) {
  int idx = blockIdx.x * 256 + threadIdx.x;
  if (idx < R * C) {
    int r = idx / C, c = idx - r * C;
    out[(size_t)c * R + r] = f2bf(in[idx]);
  }
}

// ---------------- 256x256 8-phase GEMM: C[M,N] = A[M,K] * B[N,K]^T ----------------
// 512 threads = 8 waves (2M x 4N), per-wave 128x64 out, BK=64, 2-deep LDS dbuf 128KiB.
// Stage order per tile u: ph1 A0(u+1) ph2 A1(u+1) ph3 B0(u+2) ph4 B1(u+2); vmcnt(4) @ph4.
template <bool OUT_BF16>
__global__ __launch_bounds__(512, 2) void gemm8p(const unsigned short* __restrict__ A, int lda,
                                                 const unsigned short* __restrict__ B, int ldb,
                                                 void* __restrict__ Cv, int ldc,
                                                 const float* __restrict__ bias, int N, int K) {
  __shared__ alignas(16) unsigned char lds[131072];  // A: [0,64K) B: [64K,128K)
  const int tid = threadIdx.x, lane = tid & 63, wave = tid >> 6;
  const int wm = wave >> 2, wn = wave & 3;
  const int nbn = N >> 8;
  const int nwg = gridDim.x;
  const int b0 = blockIdx.x;
  const int sb = (b0 & 7) * (nwg >> 3) + (b0 >> 3);  // bijective: nwg % 8 == 0
  const int bm = sb / nbn, bn = sb - bm * nbn;
  const int m0 = bm << 8, n0 = bn << 8;
  const int nkt = K >> 6;

  // staging geometry: thread covers linear LDS bytes d0=[wave*1024+lane*16] and d0+8192
  // within a 16KiB half-tile; global source is inverse-swizzled (rule #21).
  const int d0 = wave * 1024 + lane * 16;
  const int r0g = d0 >> 7;                  // 0..63
  const int c0 = (SWZ(d0) & 127) >> 1;      // elem col (16B-aligned)
  const int d1 = d0 + 8192;
  const int r1g = d1 >> 7;                  // 64..127
  const int c1 = (SWZ(d1) & 127) >> 1;

  const int fr = lane & 15, fk = lane >> 4;
  const int fkb = fk * 16;                  // byte offset of k-group within 128B row

  auto STAGE = [&](const unsigned short* __restrict__ S, int ld, int rbase, int h, int kt,
                   int bufo, int breg) {
    const unsigned short* s0 = S + (size_t)(rbase + h * 128 + r0g) * ld + kt * 64 + c0;
    const unsigned short* s1 = S + (size_t)(rbase + h * 128 + r1g) * ld + kt * 64 + c1;
    auto* lb = &lds[breg + bufo + h * 16384 + wave * 1024];  // wave-uniform dest
    GLL16(s0, lb);
    GLL16(s1, lb + 8192);
  };
  auto LDA_ = [&](int bufo, int mi, int kb) -> bf16x8 {
    const int e = (mi * 16 + fr) * 128 + kb * 64 + fkb;
    return *reinterpret_cast<const bf16x8*>(&lds[bufo + wm * 16384 + SWZ(e)]);
  };
  auto LDB_ = [&](int bufo, int ni, int kb) -> bf16x8 {
    const int e = ((wn & 1) * 64 + ni * 16 + fr) * 128 + kb * 64 + fkb;
    return *reinterpret_cast<const bf16x8*>(&lds[65536 + bufo + (wn >> 1) * 16384 + SWZ(e)]);
  };

  // prologue: tile0 (A0,A1,B0,B1) + tile1 (B0,B1) -> 12 loads; vmcnt(4) => tile0 landed
  STAGE(A, lda, m0, 0, 0, 0, 0);
  STAGE(A, lda, m0, 1, 0, 0, 0);
  STAGE(B, ldb, n0, 0, 0, 0, 65536);
  STAGE(B, ldb, n0, 1, 0, 0, 65536);
  {
    const int k1 = (nkt > 1) ? 1 : 0;
    STAGE(B, ldb, n0, 0, k1, 32768, 65536);
    STAGE(B, ldb, n0, 1, k1, 32768, 65536);
  }
  asm volatile("s_waitcnt vmcnt(4)" ::: "memory");
  __builtin_amdgcn_s_barrier();

  f32x4 acc[8][4] = {};
  bf16x8 Af[4][2], Bf[4][2];

  for (int u = 0; u < nkt; ++u) {
    const int bufo = (u & 1) * 32768;
    const int bnx = ((u + 1) & 1) * 32768;
    const int kA = (u + 1 < nkt) ? u + 1 : nkt - 1;
    const int kB = (u + 2 < nkt) ? u + 2 : nkt - 1;

    // ---- phase 1: read A m0-3 (8) + B n0-1 (4); stage A0(u+1); MFMA (m0-3 x n0-1)
#pragma unroll
    for (int mi = 0; mi < 4; ++mi) { Af[mi][0] = LDA_(bufo, mi, 0); Af[mi][1] = LDA_(bufo, mi, 1); }
#pragma unroll
    for (int ni = 0; ni < 2; ++ni) { Bf[ni][0] = LDB_(bufo, ni, 0); Bf[ni][1] = LDB_(bufo, ni, 1); }
    STAGE(A, lda, m0, 0, kA, bnx, 0);
    __builtin_amdgcn_s_barrier();
    asm volatile("s_waitcnt lgkmcnt(0)" ::: "memory");
    __builtin_amdgcn_s_setprio(1);
#pragma unroll
    for (int mi = 0; mi < 4; ++mi)
#pragma unroll
      for (int ni = 0; ni < 2; ++ni) {
        acc[mi][ni] = MFMA_BF16(Af[mi][0], Bf[ni][0], acc[mi][ni], 0, 0, 0);
        acc[mi][ni] = MFMA_BF16(Af[mi][1], Bf[ni][1], acc[mi][ni], 0, 0, 0);
      }
    __builtin_amdgcn_s_setprio(0);
    __builtin_amdgcn_s_barrier();

    // ---- phase 2: read B n2-3 (4); stage A1(u+1); MFMA (m0-3 x n2-3)
#pragma unroll
    for (int ni = 2; ni < 4; ++ni) { Bf[ni][0] = LDB_(bufo, ni, 0); Bf[ni][1] = LDB_(bufo, ni, 1); }
    STAGE(A, lda, m0, 1, kA, bnx, 0);
    __builtin_amdgcn_s_barrier();
    asm volatile("s_waitcnt lgkmcnt(0)" ::: "memory");
    __builtin_amdgcn_s_setprio(1);
#pragma unroll
    for (int mi = 0; mi < 4; ++mi)
#pragma unroll
      for (int ni = 2; ni < 4; ++ni) {
        acc[mi][ni] = MFMA_BF16(Af[mi][0], Bf[ni][0], acc[mi][ni], 0, 0, 0);
        acc[mi][ni] = MFMA_BF16(Af[mi][1], Bf[ni][1], acc[mi][ni], 0, 0, 0);
      }
    __builtin_amdgcn_s_setprio(0);
    __builtin_amdgcn_s_barrier();

    // ---- phase 3: read A m4-7 (8); stage B0(u+2); MFMA (m4-7 x n0-1) [B regs held]
#pragma unroll
    for (int mi = 0; mi < 4; ++mi) { Af[mi][0] = LDA_(bufo, 4 + mi, 0); Af[mi][1] = LDA_(bufo, 4 + mi, 1); }
    STAGE(B, ldb, n0, 0, kB, bufo, 65536);
    __builtin_amdgcn_s_barrier();
    asm volatile("s_waitcnt lgkmcnt(0)" ::: "memory");
    __builtin_amdgcn_s_setprio(1);
#pragma unroll
    for (int mi = 0; mi < 4; ++mi)
#pragma unroll
      for (int ni = 0; ni < 2; ++ni) {
        acc[4 + mi][ni] = MFMA_BF16(Af[mi][0], Bf[ni][0], acc[4 + mi][ni], 0, 0, 0);
        acc[4 + mi][ni] = MFMA_BF16(Af[mi][1], Bf[ni][1], acc[4 + mi][ni], 0, 0, 0);
      }
    __builtin_amdgcn_s_setprio(0);
    __builtin_amdgcn_s_barrier();

    // ---- phase 4: no reads; stage B1(u+2); vmcnt(4) certifies tile u+1; MFMA (m4-7 x n2-3)
    STAGE(B, ldb, n0, 1, kB, bufo, 65536);
    asm volatile("s_waitcnt vmcnt(4)" ::: "memory");
    __builtin_amdgcn_s_barrier();
    __builtin_amdgcn_s_setprio(1);
#pragma unroll
    for (int mi = 0; mi < 4; ++mi)
#pragma unroll
      for (int ni = 2; ni < 4; ++ni) {
        acc[4 + mi][ni] = MFMA_BF16(Af[mi][0], Bf[ni][0], acc[4 + mi][ni], 0, 0, 0);
        acc[4 + mi][ni] = MFMA_BF16(Af[mi][1], Bf[ni][1], acc[4 + mi][ni], 0, 0, 0);
      }
    __builtin_amdgcn_s_setprio(0);
    __builtin_amdgcn_s_barrier();
  }

  // epilogue: C/D layout col = lane&15, row = (lane>>4)*4 + r
  const int er = fk << 2;
#pragma unroll
  for (int mi = 0; mi < 8; ++mi)
#pragma unroll
    for (int ni = 0; ni < 4; ++ni) {
      const int col = n0 + wn * 64 + ni * 16 + fr;
#pragma unroll
      for (int r = 0; r < 4; ++r) {
        const size_t row = (size_t)(m0 + wm * 128 + mi * 16 + er + r);
        if (OUT_BF16)
          ((unsigned short*)Cv)[row * ldc + col] = f2bf(acc[mi][ni][r]);
        else
          ((float*)Cv)[row * ldc + col] = acc[mi][ni][r] + bias[col];
      }
    }
}

// ---------------- windowed attention ----------------
__device__ __forceinline__ int region_of(int wy, int wx, int t) {
  int yr = wy * 8 + (t >> 3);
  int xr = wx * 8 + (t & 7);
  int ry = (yr < 24) ? 0 : ((yr < 28) ? 1 : 2);
  int rx = (xr < 24) ? 0 : ((xr < 28) ? 1 : 2);
  return ry * 3 + rx;
}

__global__ __launch_bounds__(256) void win_attn(const unsigned short* __restrict__ qkv,
                                                const float* __restrict__ bias_table,
                                                unsigned short* __restrict__ out,
                                                int nb16) {
  __shared__ alignas(16) unsigned short vt[4][64][72];
  __shared__ alignas(16) unsigned short pl[4][64][72];
  __shared__ unsigned short bias_sh[225 * 16];

  const int tid = threadIdx.x, lane = tid & 63, wave = tid >> 6;
  const int bid = blockIdx.x;
  const int g = bid / nb16;
  const int bw = bid - g * nb16;
  const int b = bw >> 4, w = bw & 15;
  const int wy = w >> 2, wx = w & 3;
  const int shift = g ? 4 : 0;

  for (int i = tid; i < 225 * 16; i += 256) bias_sh[i] = f2bf(bias_table[i]);
  __syncthreads();

  const int r0 = lane & 15, hi4 = lane >> 4;

  for (int hh = 0; hh < 2; ++hh) {
    const int head = g * 8 + wave * 2 + hh;
    const int qcol = head * 64;

    bf16x8 qf[4][2], kf[4][2];
#pragma unroll
    for (int mi = 0; mi < 4; ++mi) {
      const int t = mi * 16 + r0;
      const int y = (wy * 8 + (t >> 3) + shift) & 31;
      const int x = (wx * 8 + (t & 7) + shift) & 31;
      const size_t base = (size_t)((b << 10) + (y << 5) + x) * 3072 + qcol;
#pragma unroll
      for (int kb = 0; kb < 2; ++kb) {
        const int d = kb * 32 + hi4 * 8;
        qf[mi][kb] = *reinterpret_cast<const bf16x8*>(&qkv[base + d]);
        kf[mi][kb] = *reinterpret_cast<const bf16x8*>(&qkv[base + 1024 + d]);
      }
    }

    {
      const int y = (wy * 8 + (lane >> 3) + shift) & 31;
      const int x = (wx * 8 + (lane & 7) + shift) & 31;
      const unsigned short* vsrc =
          qkv + (size_t)((b << 10) + (y << 5) + x) * 3072 + 2048 + qcol;
#pragma unroll
      for (int d0 = 0; d0 < 8; ++d0) {
        u16x8 vv = *reinterpret_cast<const u16x8*>(&vsrc[d0 * 8]);
#pragma unroll
        for (int jj = 0; jj < 8; ++jj) vt[wave][d0 * 8 + jj][lane] = vv[jj];
      }
    }

    f32x4 s[4][4] = {};
#pragma unroll
    for (int mi = 0; mi < 4; ++mi)
#pragma unroll
      for (int ni = 0; ni < 4; ++ni) {
        s[mi][ni] = MFMA_BF16(qf[mi][0], kf[ni][0], s[mi][ni], 0, 0, 0);
        s[mi][ni] = MFMA_BF16(qf[mi][1], kf[ni][1], s[mi][ni], 0, 0, 0);
      }

    int rj[4];
#pragma unroll
    for (int ni = 0; ni < 4; ++ni) rj[ni] = region_of(wy, wx, ni * 16 + r0);
    float rinv[4][4];
#pragma unroll
    for (int mi = 0; mi < 4; ++mi) {
#pragma unroll
      for (int r = 0; r < 4; ++r) {
        const int it = mi * 16 + hi4 * 4 + r;
        const int iy = it >> 3, ix = it & 7;
        const int ri = region_of(wy, wx, it);
        float vals[4], vmax = -1e30f;
#pragma unroll
        for (int ni = 0; ni < 4; ++ni) {
          const int jt = ni * 16 + r0;
          const int ridx = (iy - (jt >> 3) + 7) * 15 + (ix - (jt & 7) + 7);
          float v = s[mi][ni][r] * 0.125f + bf2f(bias_sh[ridx * 16 + head]);
          if (g && ri != rj[ni]) v = -1e9f;
          vals[ni] = v;
          vmax = fmaxf(vmax, v);
        }
        vmax = fmaxf(vmax, __shfl_xor(vmax, 1));
        vmax = fmaxf(vmax, __shfl_xor(vmax, 2));
        vmax = fmaxf(vmax, __shfl_xor(vmax, 4));
        vmax = fmaxf(vmax, __shfl_xor(vmax, 8));
        float ssum = 0.f;
#pragma unroll
        for (int ni = 0; ni < 4; ++ni) {
          float p = __expf(vals[ni] - vmax);
          ssum += p;
          s[mi][ni][r] = p;
        }
        ssum += __shfl_xor(ssum, 1);
        ssum += __shfl_xor(ssum, 2);
        ssum += __shfl_xor(ssum, 4);
        ssum += __shfl_xor(ssum, 8);
        rinv[mi][r] = 1.0f / ssum;
      }
    }

#pragma unroll
    for (int mi = 0; mi < 4; ++mi)
#pragma unroll
      for (int ni = 0; ni < 4; ++ni)
#pragma unroll
        for (int r = 0; r < 4; ++r)
          pl[wave][mi * 16 + hi4 * 4 + r][ni * 16 + r0] = f2bf(s[mi][ni][r]);

    f32x4 o[4][4] = {};
#pragma unroll
    for (int kb = 0; kb < 2; ++kb) {
      bf16x8 pf[4], vf[4];
#pragma unroll
      for (int mi = 0; mi < 4; ++mi)
        pf[mi] = *reinterpret_cast<const bf16x8*>(&pl[wave][mi * 16 + r0][kb * 32 + hi4 * 8]);
#pragma unroll
      for (int di = 0; di < 4; ++di)
        vf[di] = *reinterpret_cast<const bf16x8*>(&vt[wave][di * 16 + r0][kb * 32 + hi4 * 8]);
#pragma unroll
      for (int mi = 0; mi < 4; ++mi)
#pragma unroll
        for (int di = 0; di < 4; ++di)
          o[mi][di] = MFMA_BF16(pf[mi], vf[di], o[mi][di], 0, 0, 0);
    }

#pragma unroll
    for (int mi = 0; mi < 4; ++mi)
#pragma unroll
      for (int r = 0; r < 4; ++r) {
        const int it = mi * 16 + hi4 * 4 + r;
        const int y = (wy * 8 + (it >> 3) + shift) & 31;
        const int x = (wx * 8 + (it & 7) + shift) & 31;
        unsigned short* op = out + (size_t)((b << 10) + (y << 5) + x) * 3072 + head * 64;
        const float rv = rinv[mi][r];
#pragma unroll
        for (int di = 0; di < 4; ++di) op[di * 16 + r0] = f2bf(o[mi][di][r] * rv);
      }
  }
}

// ---------------- launcher ----------------
extern "C" void kernel_launch(void* const* d_in, const int* in_sizes, int n_in,
                              void* d_out, int out_size, void* d_ws, size_t ws_size,
                              hipStream_t stream) {
  const float* x = (const float*)d_in[0];
  const float* w_qkv = (const float*)d_in[1];
  const float* bias_table = (const float*)d_in[2];
  const float* w_out = (const float*)d_in[3];
  const float* b_out = (const float*)d_in[4];
  float* out = (float*)d_out;

  int S = 1;
  for (; S < 16; S <<= 1) {
    size_t need = 2ull * (2097152ull + 234881024ull / (size_t)S);
    if (need <= ws_size) break;
  }
  const int Mc = 65536 / S;
  const int nb = 64 / S;

  unsigned short* wqt = (unsigned short*)d_ws;
  unsigned short* wot = wqt + (size_t)1572864;
  unsigned short* xb  = wot + (size_t)524288;
  unsigned short* qkv = xb + (size_t)Mc * 512;

  cvt_T_kernel<<<6144, 256, 0, stream>>>(w_qkv, wqt, 512, 3072);
  cvt_T_kernel<<<2048, 256, 0, stream>>>(w_out, wot, 1024, 512);

  for (int c = 0; c < S; ++c) {
    const float* xc = x + (size_t)c * Mc * 512;
    cvt_x_kernel<<<2048, 256, 0, stream>>>(xc, xb, Mc * 128);
    gemm8p<true><<<(Mc >> 8) * 12, 512, 0, stream>>>(xb, 512, wqt, 512, (void*)qkv, 3072,
                                                     nullptr, 3072, 512);
    win_attn<<<2 * nb * 16, 256, 0, stream>>>(qkv, bias_table, qkv, nb * 16);
    gemm8p<false><<<(Mc >> 8) * 2, 512, 0, stream>>>(qkv, 3072, wot, 1024,
                                                     (void*)(out + (size_t)c * Mc * 512), 512,
                                                     b_out, 512, 1024);
  }
}